// Round 6
// baseline (803.806 us; speedup 1.0000x reference)
//
#include <hip/hip_runtime.h>
#include <hip/hip_bf16.h>

#define BB   4
#define NN   8192
#define EE   65536
#define FOBS 128
#define FH   256
#define FOUT 1024
#define NLOG 18
#define BKT  64

#define GRIDB 256
#define NT    512
#define MAGIC 0x1B7E4A93

typedef __attribute__((ext_vector_type(8))) short frag8;
typedef __attribute__((ext_vector_type(4))) float f32x4;

__device__ __forceinline__ ushort f2b(float v) {
    __hip_bfloat16 h = __float2bfloat16(v);
    return *reinterpret_cast<ushort*>(&h);
}
__device__ __forceinline__ float blo(uint u) { return __uint_as_float(u << 16); }
__device__ __forceinline__ float bhi(uint u) { return __uint_as_float(u & 0xffff0000u); }

__device__ __forceinline__ void gld16(const void* g, void* l) {
    __builtin_amdgcn_global_load_lds(
        (const __attribute__((address_space(1))) unsigned*)g,
        (__attribute__((address_space(3))) unsigned*)l, 16, 0, 0);
}

#define XB2_N  (BB * NN * FOBS / 2)
#define W0_N   (FOBS * FH)
#define W1_N   (FH * FOUT)
#define WH_N   (19 * FOUT)
#define CUR_N  (BB * NN)
#define OUTI_N (BB * NN * 19)
#define PREP_TOTAL (XB2_N + W0_N + W1_N + WH_N + CUR_N + OUTI_N)

// ---- global barrier: bar[0]=init flag, bar[1]=arrive cnt, bar[2]=generation ----
// Monotonic generation => safe across graph replays whether or not ws is re-poisoned.
__device__ __forceinline__ void gbar(int* bar) {
    __threadfence();                 // publish this thread's phase writes (L2 wb, cross-XCD)
    __syncthreads();
    if (threadIdx.x == 0) {
        int g = __hip_atomic_load(&bar[2], __ATOMIC_RELAXED, __HIP_MEMORY_SCOPE_AGENT);
        int a = __hip_atomic_fetch_add(&bar[1], 1, __ATOMIC_ACQ_REL, __HIP_MEMORY_SCOPE_AGENT);
        if (a == GRIDB - 1) {
            __hip_atomic_store(&bar[1], 0, __ATOMIC_RELAXED, __HIP_MEMORY_SCOPE_AGENT);
            __hip_atomic_store(&bar[2], g + 1, __ATOMIC_RELEASE, __HIP_MEMORY_SCOPE_AGENT);
        } else {
            while (__hip_atomic_load(&bar[2], __ATOMIC_ACQUIRE, __HIP_MEMORY_SCOPE_AGENT) == g)
                __builtin_amdgcn_s_sleep(2);
        }
    }
    __syncthreads();
    __threadfence();                 // acquire side: invalidate before reading others' data
}

// ---------------- gather bodies (round-5 math) ----------------
__device__ __forceinline__ void agg_node_b128(
    const uint* __restrict__ xb, const int* __restrict__ cnt, const ushort* __restrict__ bkt,
    int n, int lane, uint* __restrict__ dst)
{
    int cn = cnt[n];
    float wn = rsqrtf((float)cn + 1.0f);
    int deg = min(cn, BKT);

    uint u = xb[(size_t)n * 64 + lane];
    float w2s = wn * wn;
    float a0 = w2s * blo(u), a1 = w2s * bhi(u);

    for (int i = 0; i < deg; i += 8) {
        uint4 va = *(const uint4*)&bkt[i];
        int s0 = (int)(va.x & 0xffffu);
        int s1 = (i + 1 < deg) ? (int)(va.x >> 16) : s0;
        int s2 = (i + 2 < deg) ? (int)(va.y & 0xffffu) : s0;
        int s3 = (i + 3 < deg) ? (int)(va.y >> 16) : s0;
        int s4 = (i + 4 < deg) ? (int)(va.z & 0xffffu) : s0;
        int s5 = (i + 5 < deg) ? (int)(va.z >> 16) : s0;
        int s6 = (i + 6 < deg) ? (int)(va.w & 0xffffu) : s0;
        int s7 = (i + 7 < deg) ? (int)(va.w >> 16) : s0;
        float w0 = rsqrtf((float)cnt[s0] + 1.0f) * wn;
        float w1 = (i + 1 < deg) ? rsqrtf((float)cnt[s1] + 1.0f) * wn : 0.0f;
        float w2 = (i + 2 < deg) ? rsqrtf((float)cnt[s2] + 1.0f) * wn : 0.0f;
        float w3 = (i + 3 < deg) ? rsqrtf((float)cnt[s3] + 1.0f) * wn : 0.0f;
        float w4 = (i + 4 < deg) ? rsqrtf((float)cnt[s4] + 1.0f) * wn : 0.0f;
        float w5 = (i + 5 < deg) ? rsqrtf((float)cnt[s5] + 1.0f) * wn : 0.0f;
        float w6 = (i + 6 < deg) ? rsqrtf((float)cnt[s6] + 1.0f) * wn : 0.0f;
        float w7 = (i + 7 < deg) ? rsqrtf((float)cnt[s7] + 1.0f) * wn : 0.0f;
        uint r0 = xb[(size_t)s0 * 64 + lane], r1 = xb[(size_t)s1 * 64 + lane];
        uint r2 = xb[(size_t)s2 * 64 + lane], r3 = xb[(size_t)s3 * 64 + lane];
        uint r4 = xb[(size_t)s4 * 64 + lane], r5 = xb[(size_t)s5 * 64 + lane];
        uint r6 = xb[(size_t)s6 * 64 + lane], r7 = xb[(size_t)s7 * 64 + lane];
        a0 += w0 * blo(r0) + w1 * blo(r1) + w2 * blo(r2) + w3 * blo(r3)
            + w4 * blo(r4) + w5 * blo(r5) + w6 * blo(r6) + w7 * blo(r7);
        a1 += w0 * bhi(r0) + w1 * bhi(r1) + w2 * bhi(r2) + w3 * bhi(r3)
            + w4 * bhi(r4) + w5 * bhi(r5) + w6 * bhi(r6) + w7 * bhi(r7);
    }
    *dst = (uint)f2b(a0) | ((uint)f2b(a1) << 16);
}

__device__ __forceinline__ void agg_node_b256(
    const uint2* __restrict__ xb, const int* __restrict__ cnt, const ushort* __restrict__ bkt,
    int n, int lane, uint2* __restrict__ dst)
{
    int cn = cnt[n];
    float wn = rsqrtf((float)cn + 1.0f);
    int deg = min(cn, BKT);

    uint2 u = xb[(size_t)n * 64 + lane];
    float w2s = wn * wn;
    float a0 = w2s * blo(u.x), a1 = w2s * bhi(u.x), a2 = w2s * blo(u.y), a3 = w2s * bhi(u.y);

    for (int i = 0; i < deg; i += 8) {
        uint4 va = *(const uint4*)&bkt[i];
        int s0 = (int)(va.x & 0xffffu);
        int s1 = (i + 1 < deg) ? (int)(va.x >> 16) : s0;
        int s2 = (i + 2 < deg) ? (int)(va.y & 0xffffu) : s0;
        int s3 = (i + 3 < deg) ? (int)(va.y >> 16) : s0;
        int s4 = (i + 4 < deg) ? (int)(va.z & 0xffffu) : s0;
        int s5 = (i + 5 < deg) ? (int)(va.z >> 16) : s0;
        int s6 = (i + 6 < deg) ? (int)(va.w & 0xffffu) : s0;
        int s7 = (i + 7 < deg) ? (int)(va.w >> 16) : s0;
        float w0 = rsqrtf((float)cnt[s0] + 1.0f) * wn;
        float w1 = (i + 1 < deg) ? rsqrtf((float)cnt[s1] + 1.0f) * wn : 0.0f;
        float w2 = (i + 2 < deg) ? rsqrtf((float)cnt[s2] + 1.0f) * wn : 0.0f;
        float w3 = (i + 3 < deg) ? rsqrtf((float)cnt[s3] + 1.0f) * wn : 0.0f;
        float w4 = (i + 4 < deg) ? rsqrtf((float)cnt[s4] + 1.0f) * wn : 0.0f;
        float w5 = (i + 5 < deg) ? rsqrtf((float)cnt[s5] + 1.0f) * wn : 0.0f;
        float w6 = (i + 6 < deg) ? rsqrtf((float)cnt[s6] + 1.0f) * wn : 0.0f;
        float w7 = (i + 7 < deg) ? rsqrtf((float)cnt[s7] + 1.0f) * wn : 0.0f;
        uint2 r0 = xb[(size_t)s0 * 64 + lane], r1 = xb[(size_t)s1 * 64 + lane];
        uint2 r2 = xb[(size_t)s2 * 64 + lane], r3 = xb[(size_t)s3 * 64 + lane];
        uint2 r4 = xb[(size_t)s4 * 64 + lane], r5 = xb[(size_t)s5 * 64 + lane];
        uint2 r6 = xb[(size_t)s6 * 64 + lane], r7 = xb[(size_t)s7 * 64 + lane];
        a0 += w0 * blo(r0.x) + w1 * blo(r1.x) + w2 * blo(r2.x) + w3 * blo(r3.x)
            + w4 * blo(r4.x) + w5 * blo(r5.x) + w6 * blo(r6.x) + w7 * blo(r7.x);
        a1 += w0 * bhi(r0.x) + w1 * bhi(r1.x) + w2 * bhi(r2.x) + w3 * bhi(r3.x)
            + w4 * bhi(r4.x) + w5 * bhi(r5.x) + w6 * bhi(r6.x) + w7 * bhi(r7.x);
        a2 += w0 * blo(r0.y) + w1 * blo(r1.y) + w2 * blo(r2.y) + w3 * blo(r3.y)
            + w4 * blo(r4.y) + w5 * blo(r5.y) + w6 * blo(r6.y) + w7 * blo(r7.y);
        a3 += w0 * bhi(r0.y) + w1 * bhi(r1.y) + w2 * bhi(r2.y) + w3 * bhi(r3.y)
            + w4 * bhi(r4.y) + w5 * bhi(r5.y) + w6 * bhi(r6.y) + w7 * bhi(r7.y);
    }
    uint2 o;
    o.x = (uint)f2b(a0) | ((uint)f2b(a1) << 16);
    o.y = (uint)f2b(a2) | ((uint)f2b(a3) << 16);
    *dst = o;
}

// ---------------- gemm1 tile, 512 threads (8 waves, 2m x 4n), K=128 ----------------
__device__ __forceinline__ void gemm1_tile512(
    char* __restrict__ As, char* __restrict__ Bs,
    const ushort* __restrict__ A, const ushort* __restrict__ BT,
    const float* __restrict__ bias, ushort* __restrict__ C,
    int bn, int bm, int t)
{
    const int K = FOBS, N = FH;
    int lane = t & 63, w = t >> 6;
    int wm = w >> 2, wn = w & 3;
    int l15 = lane & 15, quad = lane >> 4;
    int rsub = lane >> 3, colb = (lane & 7) * 16;

    f32x4 acc[4][2] = {};
    const char* Abase = (const char*)(A + (size_t)(bm * 128) * K);
    const char* Bbase = (const char*)(BT + (size_t)(bn * 128) * K);

    for (int k0 = 0; k0 < K; k0 += 64) {
#pragma unroll
        for (int c = 0; c < 2; ++c) {
            int grp = c * 8 + w;              // 0..15
            int row = grp * 8 + rsub;
            int gcol = k0 * 2 + (colb ^ ((row & 7) << 4));
            gld16(Abase + (size_t)row * (K * 2) + gcol, As + grp * 1024);
            gld16(Bbase + (size_t)row * (K * 2) + gcol, Bs + grp * 1024);
        }
        __syncthreads();
#pragma unroll
        for (int kk = 0; kk < 64; kk += 32) {
            frag8 af[4], bf[2];
#pragma unroll
            for (int i = 0; i < 4; ++i) {
                int r = wm * 64 + i * 16 + l15;
                int cb = (kk * 2 + quad * 16) ^ ((r & 7) << 4);
                af[i] = *(const frag8*)(As + r * 128 + cb);
            }
#pragma unroll
            for (int j = 0; j < 2; ++j) {
                int r = wn * 32 + j * 16 + l15;
                int cb = (kk * 2 + quad * 16) ^ ((r & 7) << 4);
                bf[j] = *(const frag8*)(Bs + r * 128 + cb);
            }
#pragma unroll
            for (int i = 0; i < 4; ++i)
#pragma unroll
                for (int j = 0; j < 2; ++j)
                    acc[i][j] = __builtin_amdgcn_mfma_f32_16x16x32_bf16(af[i], bf[j], acc[i][j], 0, 0, 0);
        }
        __syncthreads();
    }

#pragma unroll
    for (int j = 0; j < 2; ++j) {
        int col = bn * 128 + wn * 32 + j * 16 + l15;
        float bcol = bias[col];
#pragma unroll
        for (int i = 0; i < 4; ++i) {
#pragma unroll
            for (int r = 0; r < 4; ++r) {
                int row = bm * 128 + wm * 64 + i * 16 + quad * 4 + r;
                float v = fmaxf(acc[i][j][r] + bcol, 0.0f);
                C[(size_t)row * N + col] = f2b(v);
            }
        }
    }
}

// ---------------- gemm2+heads tile, 512 threads (round-2 structure widened) ----------------
__device__ __forceinline__ void gemm2_tile512(
    char* __restrict__ smemc,
    const ushort* __restrict__ hagg_all, const ushort* __restrict__ W1T,
    const float* __restrict__ b1, const ushort* __restrict__ WT19,
    float* __restrict__ out_logits, float* __restrict__ out_values,
    int bm, int sp, int g, int t)
{
    char* AsB = smemc;
    char* BsB = smemc + 16384;
    ushort* Ct = (ushort*)smemc;                          // [128][136] = 34816B
    ushort (*wt)[136] = (ushort (*)[136])(smemc + 34816); // 20*136*2 = 5440B

    int lane = t & 63, w = t >> 6;
    int wm = w >> 2, wn = w & 3;
    int l15 = lane & 15, quad = lane >> 4;
    int rsub = lane >> 3, colb = (lane & 7) * 16;

    const char* A0 = (const char*)(hagg_all + ((size_t)g * NN + bm * 128) * FH);

    if (t < 136) wt[19][t] = 0;

    f32x4 hacc[2] = {};

    for (int bi = 0; bi < 4; ++bi) {
        int bn = sp * 4 + bi;
        __syncthreads();

        for (int idx = t; idx < 19 * 16; idx += NT) {
            int row = idx >> 4, c8 = (idx & 15) * 8;
            *(uint4*)&wt[row][c8] = *(const uint4*)(WT19 + (size_t)row * FOUT + bn * 128 + c8);
        }

        f32x4 acc[4][2] = {};
        const char* Bbase = (const char*)(W1T + (size_t)(bn * 128) * FH);

        for (int k0 = 0; k0 < FH; k0 += 64) {
#pragma unroll
            for (int c = 0; c < 2; ++c) {
                int grp = c * 8 + w;
                int row = grp * 8 + rsub;
                int gcol = k0 * 2 + (colb ^ ((row & 7) << 4));
                gld16(A0 + (size_t)row * (FH * 2) + gcol, AsB + grp * 1024);
                gld16(Bbase + (size_t)row * (FH * 2) + gcol, BsB + grp * 1024);
            }
            __syncthreads();
#pragma unroll
            for (int kk = 0; kk < 64; kk += 32) {
                frag8 af[4], bf[2];
#pragma unroll
                for (int i = 0; i < 4; ++i) {
                    int r = wm * 64 + i * 16 + l15;
                    int cb = (kk * 2 + quad * 16) ^ ((r & 7) << 4);
                    af[i] = *(const frag8*)(AsB + r * 128 + cb);
                }
#pragma unroll
                for (int j = 0; j < 2; ++j) {
                    int r = wn * 32 + j * 16 + l15;
                    int cb = (kk * 2 + quad * 16) ^ ((r & 7) << 4);
                    bf[j] = *(const frag8*)(BsB + r * 128 + cb);
                }
#pragma unroll
                for (int i = 0; i < 4; ++i)
#pragma unroll
                    for (int j = 0; j < 2; ++j)
                        acc[i][j] = __builtin_amdgcn_mfma_f32_16x16x32_bf16(af[i], bf[j], acc[i][j], 0, 0, 0);
            }
            __syncthreads();
        }

#pragma unroll
        for (int j = 0; j < 2; ++j) {
            int colL = wn * 32 + j * 16 + l15;
            float bcol = b1[bn * 128 + colL];
#pragma unroll
            for (int i = 0; i < 4; ++i) {
                int rowL = wm * 64 + i * 16 + quad * 4;
#pragma unroll
                for (int r = 0; r < 4; ++r) {
                    float v = fmaxf(acc[i][j][r] + bcol, 0.0f);
                    Ct[(size_t)(rowL + r) * 136 + colL] = f2b(v);
                }
            }
        }
        __syncthreads();

        int r1 = (l15 < 3) ? (16 + l15) : 19;
#pragma unroll
        for (int kk = 0; kk < 128; kk += 32) {
            frag8 b0 = *(const frag8*)&wt[l15][kk + quad * 8];
            frag8 bO = *(const frag8*)&wt[r1][kk + quad * 8];
            frag8 af = *(const frag8*)&Ct[(size_t)(w * 16 + l15) * 136 + kk + quad * 8];
            hacc[0] = __builtin_amdgcn_mfma_f32_16x16x32_bf16(af, b0, hacc[0], 0, 0, 0);
            hacc[1] = __builtin_amdgcn_mfma_f32_16x16x32_bf16(af, bO, hacc[1], 0, 0, 0);
        }
        __syncthreads();
    }

#pragma unroll
    for (int r = 0; r < 4; ++r) {
        int node = bm * 128 + w * 16 + quad * 4 + r;
        size_t gn = (size_t)g * NN + node;
        atomicAdd(&out_logits[gn * NLOG + l15], hacc[0][r]);
        if (l15 < 2)       atomicAdd(&out_logits[gn * NLOG + 16 + l15], hacc[1][r]);
        else if (l15 == 2) atomicAdd(&out_values[gn], hacc[1][r]);
    }
}

// ---------------- the megakernel ----------------
__global__ __launch_bounds__(NT) void mega(
    const float* __restrict__ nodes, const int* __restrict__ edges,
    const float* __restrict__ W0, const float* __restrict__ b0,
    const float* __restrict__ W1, const float* __restrict__ b1,
    const float* __restrict__ Wl, const float* __restrict__ bl,
    const float* __restrict__ Wv, const float* __restrict__ bv,
    int* __restrict__ cursor, ushort* __restrict__ W0T,
    ushort* __restrict__ W1T, ushort* __restrict__ WT19,
    uint* __restrict__ xb, ushort* __restrict__ bucket,
    ushort* __restrict__ xagg, ushort* __restrict__ h1b, ushort* __restrict__ hagg,
    int* __restrict__ bar,
    float* __restrict__ out_logits, float* __restrict__ out_values)
{
    __shared__ __align__(16) char smem[40256];
    int t = threadIdx.x, bid = blockIdx.x;
    int wv = t >> 6, lane = t & 63;

    // ---- entry: init barrier state (poison-safe, replay-safe) ----
    if (bid == 0 && t == 0) {
        if (__hip_atomic_load(&bar[0], __ATOMIC_RELAXED, __HIP_MEMORY_SCOPE_AGENT) != MAGIC) {
            __hip_atomic_store(&bar[1], 0, __ATOMIC_RELAXED, __HIP_MEMORY_SCOPE_AGENT);
            __hip_atomic_store(&bar[2], 0, __ATOMIC_RELAXED, __HIP_MEMORY_SCOPE_AGENT);
            __hip_atomic_store(&bar[0], MAGIC, __ATOMIC_RELEASE, __HIP_MEMORY_SCOPE_AGENT);
        }
    }
    if (t == 0) {
        while (__hip_atomic_load(&bar[0], __ATOMIC_ACQUIRE, __HIP_MEMORY_SCOPE_AGENT) != MAGIC)
            __builtin_amdgcn_s_sleep(2);
    }
    __syncthreads();

    // ---- phase 1: prep ----
    for (int idx = bid * NT + t; idx < PREP_TOTAL; idx += GRIDB * NT) {
        int i = idx;
        if (i < XB2_N) {
            float2 xx = ((const float2*)nodes)[i];
            xb[i] = (uint)f2b(xx.x) | ((uint)f2b(xx.y) << 16);
        } else {
            i -= XB2_N;
            if (i < W0_N) {
                int n = i / FOBS, k = i - n * FOBS;
                W0T[i] = f2b(W0[(size_t)k * FH + n]);
            } else {
                i -= W0_N;
                if (i < W1_N) {
                    int n = i / FH, k = i - n * FH;
                    W1T[i] = f2b(W1[(size_t)k * FOUT + n]);
                } else {
                    i -= W1_N;
                    if (i < WH_N) {
                        int o = i >> 10, k = i & (FOUT - 1);
                        WT19[i] = f2b((o < NLOG) ? Wl[(size_t)k * NLOG + o] : Wv[k]);
                    } else {
                        i -= WH_N;
                        if (i < CUR_N) {
                            cursor[i] = 0;
                        } else {
                            i -= CUR_N;
                            int gn = i / 19, o = i - gn * 19;
                            if (o < NLOG) out_logits[(size_t)gn * NLOG + o] = bl[o];
                            else          out_values[gn] = bv[0];
                        }
                    }
                }
            }
        }
    }
    gbar(bar);

    // ---- phase 2: bucket fill ----
    for (int el = bid * NT + t; el < BB * EE; el += GRIDB * NT) {
        int g = el >> 16, e = el & (EE - 1);
        const int* src = edges + (size_t)g * 2 * EE;
        int d = src[EE + e];
        int slot = atomicAdd(&cursor[(size_t)g * NN + d], 1);
        if (slot < BKT) bucket[((size_t)g * NN + d) * BKT + slot] = (ushort)src[e];
    }
    gbar(bar);

    // ---- phase 3: layer-1 aggregation (2048 waves, 16 nodes each) ----
    for (int nw = bid * 8 + wv; nw < BB * NN; nw += GRIDB * 8) {
        int g = nw >> 13, n = nw & (NN - 1);
        agg_node_b128(xb + (size_t)g * NN * 64,
                      cursor + (size_t)g * NN,
                      bucket + ((size_t)g * NN + n) * BKT,
                      n, lane,
                      (uint*)xagg + ((size_t)g * NN + n) * 64 + lane);
    }
    gbar(bar);

    // ---- phase 4: layer-1 GEMM (512 tiles, 2 per block) ----
#pragma unroll
    for (int ti = 0; ti < 2; ++ti) {
        int tile = bid * 2 + ti;
        int bn = tile & 1, bm = (tile >> 1) & 63, g = tile >> 7;
        gemm1_tile512(smem, smem + 16384,
                      xagg + (size_t)g * NN * FOBS, W0T, b0,
                      h1b + (size_t)g * NN * FH, bn, bm, t);
        __syncthreads();
    }
    gbar(bar);

    // ---- phase 5: layer-2 aggregation ----
    for (int nw = bid * 8 + wv; nw < BB * NN; nw += GRIDB * 8) {
        int g = nw >> 13, n = nw & (NN - 1);
        agg_node_b256((const uint2*)h1b + (size_t)g * NN * 64,
                      cursor + (size_t)g * NN,
                      bucket + ((size_t)g * NN + n) * BKT,
                      n, lane,
                      (uint2*)hagg + ((size_t)g * NN + n) * 64 + lane);
    }
    gbar(bar);

    // ---- phase 6: layer-2 GEMM + heads (512 tiles, 2 per block; atomic combine) ----
#pragma unroll
    for (int ti = 0; ti < 2; ++ti) {
        int tile = bid * 2 + ti;
        int sp = tile & 1, bm = (tile >> 1) & 63, g = tile >> 7;
        gemm2_tile512(smem, hagg, W1T, b1, WT19, out_logits, out_values, bm, sp, g, t);
        __syncthreads();
    }
}

// ---------------- launcher ----------------
extern "C" void kernel_launch(void* const* d_in, const int* in_sizes, int n_in,
                              void* d_out, int out_size, void* d_ws, size_t ws_size,
                              hipStream_t stream) {
    const float* nodes = (const float*)d_in[0];
    const int*   edges = (const int*)d_in[1];
    const float* W0 = (const float*)d_in[2];
    const float* b0 = (const float*)d_in[3];
    const float* W1 = (const float*)d_in[4];
    const float* b1 = (const float*)d_in[5];
    const float* Wl = (const float*)d_in[6];
    const float* bl = (const float*)d_in[7];
    const float* Wv = (const float*)d_in[8];
    const float* bv = (const float*)d_in[9];

    float* out_logits = (float*)d_out;
    float* out_values = out_logits + (size_t)BB * NN * NLOG;

    char* ws = (char*)d_ws;
    int*    cursor  = (int*)(ws);                     // 128 KB
    ushort* W0T     = (ushort*)(ws + (128 << 10));    // 64 KB
    ushort* W1T     = (ushort*)(ws + (192 << 10));    // 512 KB
    ushort* WT19    = (ushort*)(ws + (704 << 10));    // 38 KB
    int*    bar     = (int*)(ws + (896 << 10));       // 16 B barrier state
    uint*   xb      = (uint*)(ws + (1u << 20));       // 8 MB  [B,N,128] bf16
    ushort* bucket  = (ushort*)(ws + (9u << 20));     // 4 MB  [B,N,64] ushort
    ushort* xagg_b  = (ushort*)(ws + (13u << 20));    // 8 MB  [B,N,128] bf16
    ushort* h1b     = (ushort*)(ws + (21u << 20));    // 16 MB [B,N,256] bf16
    ushort* hagg_b  = (ushort*)(ws + (37u << 20));    // 16 MB [B,N,256] bf16

    mega<<<dim3(GRIDB), dim3(NT), 0, stream>>>(
        nodes, edges, W0, b0, W1, b1, Wl, bl, Wv, bv,
        cursor, W0T, W1T, WT19, xb, bucket, xagg_b, h1b, hagg_b, bar,
        out_logits, out_values);
}

// Round 7
// 305.850 us; speedup vs baseline: 2.6281x; 2.6281x over previous
//
#include <hip/hip_runtime.h>
#include <hip/hip_bf16.h>

#define BB   4
#define NN   8192
#define EE   65536
#define FOBS 128
#define FH   256
#define FOUT 1024
#define NLOG 18
#define BKT  64

typedef __attribute__((ext_vector_type(8))) short frag8;
typedef __attribute__((ext_vector_type(4))) float f32x4;

__device__ __forceinline__ ushort f2b(float v) {
    __hip_bfloat16 h = __float2bfloat16(v);
    return *reinterpret_cast<ushort*>(&h);
}
__device__ __forceinline__ float blo(uint u) { return __uint_as_float(u << 16); }
__device__ __forceinline__ float bhi(uint u) { return __uint_as_float(u & 0xffff0000u); }

// async global->LDS, 16B per lane; LDS dest is wave-uniform base + lane*16
__device__ __forceinline__ void gld16(const void* g, void* l) {
    __builtin_amdgcn_global_load_lds(
        (const __attribute__((address_space(1))) unsigned*)g,
        (__attribute__((address_space(3))) unsigned*)l, 16, 0, 0);
}

// ---------------- prep: x->bf16 + weight transposes + heads pack + cursor + out init ----------------
#define XB2_N  (BB * NN * FOBS / 2)
#define W0_N   (FOBS * FH)
#define W1_N   (FH * FOUT)
#define WH_N   (19 * FOUT)
#define CUR_N  (BB * NN)
#define OUTI_N (BB * NN * 19)
#define PREP_TOTAL (XB2_N + W0_N + W1_N + WH_N + CUR_N + OUTI_N)

__global__ void prep_kernel(const float* __restrict__ nodes, uint* __restrict__ xb,
                            const float* __restrict__ W0, ushort* __restrict__ W0T,
                            const float* __restrict__ W1, ushort* __restrict__ W1T,
                            const float* __restrict__ Wl, const float* __restrict__ Wv,
                            ushort* __restrict__ WT19, int* __restrict__ cursor,
                            const float* __restrict__ bl, const float* __restrict__ bv,
                            float* __restrict__ out_logits, float* __restrict__ out_values) {
    int idx = blockIdx.x * blockDim.x + threadIdx.x;
    if (idx < XB2_N) {
        float2 xx = ((const float2*)nodes)[idx];
        xb[idx] = (uint)f2b(xx.x) | ((uint)f2b(xx.y) << 16);
        return;
    }
    idx -= XB2_N;
    if (idx < W0_N) {
        int n = idx / FOBS, k = idx - n * FOBS;
        W0T[idx] = f2b(W0[(size_t)k * FH + n]);
        return;
    }
    idx -= W0_N;
    if (idx < W1_N) {
        int n = idx / FH, k = idx - n * FH;
        W1T[idx] = f2b(W1[(size_t)k * FOUT + n]);
        return;
    }
    idx -= W1_N;
    if (idx < WH_N) {
        int o = idx >> 10, k = idx & (FOUT - 1);
        WT19[idx] = f2b((o < NLOG) ? Wl[(size_t)k * NLOG + o] : Wv[k]);
        return;
    }
    idx -= WH_N;
    if (idx < CUR_N) { cursor[idx] = 0; return; }
    idx -= CUR_N;
    if (idx < OUTI_N) {
        int gn = idx / 19, o = idx - gn * 19;
        if (o < NLOG) out_logits[(size_t)gn * NLOG + o] = bl[o];
        else          out_values[gn] = bv[0];
    }
}

// ---------------- bucket fill: direct atomic slot allocation, ushort slots ----------------
__global__ void bucket_fill(const int* __restrict__ edges, int* __restrict__ cursor,
                            ushort* __restrict__ bucket) {
    int blk = blockIdx.x;
    int xcd = blk & 7;
    int g = xcd >> 1;
    int chunk = (blk >> 3) * 2 + (xcd & 1);
    int e = chunk * 256 + threadIdx.x;
    const int* src = edges + (size_t)g * 2 * EE;
    const int* dst = src + EE;
    int d = dst[e];
    int slot = atomicAdd(&cursor[(size_t)g * NN + d], 1);
    if (slot < BKT) bucket[((size_t)g * NN + d) * BKT + slot] = (ushort)src[e];
}

// ---------------- gather 1: bf16 x rows (256B), ushort indices ----------------
__global__ __launch_bounds__(256) void gather_agg_b128(
    const uint* __restrict__ xb_all, const int* __restrict__ cnt_all,
    const ushort* __restrict__ bucket, uint* __restrict__ agg_all)
{
    int blk = blockIdx.x;
    int xcd = blk & 7;
    int g = xcd >> 1;
    int chunk = (blk >> 3) * 2 + (xcd & 1);
    int wv = threadIdx.x >> 6, lane = threadIdx.x & 63;
    int n = chunk * 4 + wv;
    const uint* xb = xb_all + (size_t)g * NN * 64;
    const int* cnt = cnt_all + (size_t)g * NN;
    const ushort* bkt = bucket + ((size_t)g * NN + n) * BKT;

    int cn = cnt[n];
    float wn = rsqrtf((float)cn + 1.0f);
    int deg = min(cn, BKT);

    uint u = xb[(size_t)n * 64 + lane];
    float w2s = wn * wn;
    float a0 = w2s * blo(u), a1 = w2s * bhi(u);

    for (int i = 0; i < deg; i += 8) {
        uint4 va = *(const uint4*)&bkt[i];           // 8 ushort indices
        int s0 = (int)(va.x & 0xffffu);
        int s1 = (i + 1 < deg) ? (int)(va.x >> 16) : s0;
        int s2 = (i + 2 < deg) ? (int)(va.y & 0xffffu) : s0;
        int s3 = (i + 3 < deg) ? (int)(va.y >> 16) : s0;
        int s4 = (i + 4 < deg) ? (int)(va.z & 0xffffu) : s0;
        int s5 = (i + 5 < deg) ? (int)(va.z >> 16) : s0;
        int s6 = (i + 6 < deg) ? (int)(va.w & 0xffffu) : s0;
        int s7 = (i + 7 < deg) ? (int)(va.w >> 16) : s0;
        float w0 = rsqrtf((float)cnt[s0] + 1.0f) * wn;
        float w1 = (i + 1 < deg) ? rsqrtf((float)cnt[s1] + 1.0f) * wn : 0.0f;
        float w2 = (i + 2 < deg) ? rsqrtf((float)cnt[s2] + 1.0f) * wn : 0.0f;
        float w3 = (i + 3 < deg) ? rsqrtf((float)cnt[s3] + 1.0f) * wn : 0.0f;
        float w4 = (i + 4 < deg) ? rsqrtf((float)cnt[s4] + 1.0f) * wn : 0.0f;
        float w5 = (i + 5 < deg) ? rsqrtf((float)cnt[s5] + 1.0f) * wn : 0.0f;
        float w6 = (i + 6 < deg) ? rsqrtf((float)cnt[s6] + 1.0f) * wn : 0.0f;
        float w7 = (i + 7 < deg) ? rsqrtf((float)cnt[s7] + 1.0f) * wn : 0.0f;
        uint r0 = xb[(size_t)s0 * 64 + lane], r1 = xb[(size_t)s1 * 64 + lane];
        uint r2 = xb[(size_t)s2 * 64 + lane], r3 = xb[(size_t)s3 * 64 + lane];
        uint r4 = xb[(size_t)s4 * 64 + lane], r5 = xb[(size_t)s5 * 64 + lane];
        uint r6 = xb[(size_t)s6 * 64 + lane], r7 = xb[(size_t)s7 * 64 + lane];
        a0 += w0 * blo(r0) + w1 * blo(r1) + w2 * blo(r2) + w3 * blo(r3)
            + w4 * blo(r4) + w5 * blo(r5) + w6 * blo(r6) + w7 * blo(r7);
        a1 += w0 * bhi(r0) + w1 * bhi(r1) + w2 * bhi(r2) + w3 * bhi(r3)
            + w4 * bhi(r4) + w5 * bhi(r5) + w6 * bhi(r6) + w7 * bhi(r7);
    }
    agg_all[((size_t)g * NN + n) * 64 + lane] = (uint)f2b(a0) | ((uint)f2b(a1) << 16);
}

// ---------------- gather 2: bf16 h1 rows (512B), ushort indices ----------------
__global__ __launch_bounds__(256) void gather_agg_b256(
    const uint2* __restrict__ xb_all, const int* __restrict__ cnt_all,
    const ushort* __restrict__ bucket, uint2* __restrict__ agg_all)
{
    int blk = blockIdx.x;
    int xcd = blk & 7;
    int g = xcd >> 1;
    int chunk = (blk >> 3) * 2 + (xcd & 1);
    int wv = threadIdx.x >> 6, lane = threadIdx.x & 63;
    int n = chunk * 4 + wv;
    const uint2* xb = xb_all + (size_t)g * NN * 64;
    const int* cnt = cnt_all + (size_t)g * NN;
    const ushort* bkt = bucket + ((size_t)g * NN + n) * BKT;

    int cn = cnt[n];
    float wn = rsqrtf((float)cn + 1.0f);
    int deg = min(cn, BKT);

    uint2 u = xb[(size_t)n * 64 + lane];
    float w2s = wn * wn;
    float a0 = w2s * blo(u.x), a1 = w2s * bhi(u.x), a2 = w2s * blo(u.y), a3 = w2s * bhi(u.y);

    for (int i = 0; i < deg; i += 8) {
        uint4 va = *(const uint4*)&bkt[i];
        int s0 = (int)(va.x & 0xffffu);
        int s1 = (i + 1 < deg) ? (int)(va.x >> 16) : s0;
        int s2 = (i + 2 < deg) ? (int)(va.y & 0xffffu) : s0;
        int s3 = (i + 3 < deg) ? (int)(va.y >> 16) : s0;
        int s4 = (i + 4 < deg) ? (int)(va.z & 0xffffu) : s0;
        int s5 = (i + 5 < deg) ? (int)(va.z >> 16) : s0;
        int s6 = (i + 6 < deg) ? (int)(va.w & 0xffffu) : s0;
        int s7 = (i + 7 < deg) ? (int)(va.w >> 16) : s0;
        float w0 = rsqrtf((float)cnt[s0] + 1.0f) * wn;
        float w1 = (i + 1 < deg) ? rsqrtf((float)cnt[s1] + 1.0f) * wn : 0.0f;
        float w2 = (i + 2 < deg) ? rsqrtf((float)cnt[s2] + 1.0f) * wn : 0.0f;
        float w3 = (i + 3 < deg) ? rsqrtf((float)cnt[s3] + 1.0f) * wn : 0.0f;
        float w4 = (i + 4 < deg) ? rsqrtf((float)cnt[s4] + 1.0f) * wn : 0.0f;
        float w5 = (i + 5 < deg) ? rsqrtf((float)cnt[s5] + 1.0f) * wn : 0.0f;
        float w6 = (i + 6 < deg) ? rsqrtf((float)cnt[s6] + 1.0f) * wn : 0.0f;
        float w7 = (i + 7 < deg) ? rsqrtf((float)cnt[s7] + 1.0f) * wn : 0.0f;
        uint2 r0 = xb[(size_t)s0 * 64 + lane], r1 = xb[(size_t)s1 * 64 + lane];
        uint2 r2 = xb[(size_t)s2 * 64 + lane], r3 = xb[(size_t)s3 * 64 + lane];
        uint2 r4 = xb[(size_t)s4 * 64 + lane], r5 = xb[(size_t)s5 * 64 + lane];
        uint2 r6 = xb[(size_t)s6 * 64 + lane], r7 = xb[(size_t)s7 * 64 + lane];
        a0 += w0 * blo(r0.x) + w1 * blo(r1.x) + w2 * blo(r2.x) + w3 * blo(r3.x)
            + w4 * blo(r4.x) + w5 * blo(r5.x) + w6 * blo(r6.x) + w7 * blo(r7.x);
        a1 += w0 * bhi(r0.x) + w1 * bhi(r1.x) + w2 * bhi(r2.x) + w3 * bhi(r3.x)
            + w4 * bhi(r4.x) + w5 * bhi(r5.x) + w6 * bhi(r6.x) + w7 * bhi(r7.x);
        a2 += w0 * blo(r0.y) + w1 * blo(r1.y) + w2 * blo(r2.y) + w3 * blo(r3.y)
            + w4 * blo(r4.y) + w5 * blo(r5.y) + w6 * blo(r6.y) + w7 * blo(r7.y);
        a3 += w0 * bhi(r0.y) + w1 * bhi(r1.y) + w2 * bhi(r2.y) + w3 * bhi(r3.y)
            + w4 * bhi(r4.y) + w5 * bhi(r5.y) + w6 * bhi(r6.y) + w7 * bhi(r7.y);
    }
    uint2 o;
    o.x = (uint)f2b(a0) | ((uint)f2b(a1) << 16);
    o.y = (uint)f2b(a2) | ((uint)f2b(a3) << 16);
    agg_all[((size_t)g * NN + n) * 64 + lane] = o;
}

// ---------------- MFMA GEMM (layer 1, batched via blockIdx.z) ----------------
__global__ __launch_bounds__(256) void mfma_gemm(
    const ushort* __restrict__ A_all, const ushort* __restrict__ BT,
    const float* __restrict__ bias, ushort* __restrict__ C_all,
    int M, int N, int K, int relu)
{
    __shared__ __align__(16) ushort As[128 * 64];
    __shared__ __align__(16) ushort Bs[128 * 64];

    int g = blockIdx.z;
    const ushort* A = A_all + (size_t)g * M * K;
    ushort* C = C_all + (size_t)g * M * N;

    int t = threadIdx.x;
    int bn = blockIdx.x, bm = blockIdx.y;
    int lane = t & 63, w = t >> 6;
    int wm = w >> 1, wn = w & 1;
    int l15 = lane & 15, quad = lane >> 4;

    f32x4 acc[4][4] = {};

    const char* Abase = (const char*)(A + (size_t)(bm * 128) * K);
    const char* Bbase = (const char*)(BT + (size_t)(bn * 128) * K);
    size_t rstride = (size_t)K * 2;

    int rsub = lane >> 3;
    int colb = (lane & 7) * 16;

    for (int k0 = 0; k0 < K; k0 += 64) {
#pragma unroll
        for (int c = 0; c < 4; ++c) {
            int grp = c * 4 + w;
            int row = grp * 8 + rsub;
            int gcol = k0 * 2 + (colb ^ ((row & 7) << 4));
            gld16(Abase + (size_t)row * rstride + gcol, (char*)As + grp * 1024);
            gld16(Bbase + (size_t)row * rstride + gcol, (char*)Bs + grp * 1024);
        }
        __syncthreads();
#pragma unroll
        for (int kk = 0; kk < 64; kk += 32) {
            frag8 af[4], bf[4];
#pragma unroll
            for (int i = 0; i < 4; ++i) {
                int r = wm * 64 + i * 16 + l15;
                int cb = (kk * 2 + quad * 16) ^ ((r & 7) << 4);
                af[i] = *(const frag8*)((const char*)As + r * 128 + cb);
            }
#pragma unroll
            for (int j = 0; j < 4; ++j) {
                int r = wn * 64 + j * 16 + l15;
                int cb = (kk * 2 + quad * 16) ^ ((r & 7) << 4);
                bf[j] = *(const frag8*)((const char*)Bs + r * 128 + cb);
            }
#pragma unroll
            for (int i = 0; i < 4; ++i)
#pragma unroll
                for (int j = 0; j < 4; ++j)
                    acc[i][j] = __builtin_amdgcn_mfma_f32_16x16x32_bf16(af[i], bf[j], acc[i][j], 0, 0, 0);
        }
        __syncthreads();
    }

#pragma unroll
    for (int i = 0; i < 4; ++i) {
#pragma unroll
        for (int j = 0; j < 4; ++j) {
            int col = bn * 128 + wn * 64 + j * 16 + l15;
            float bcol = bias[col];
#pragma unroll
            for (int r = 0; r < 4; ++r) {
                int row = bm * 128 + wm * 64 + i * 16 + quad * 4 + r;
                float v = acc[i][j][r] + bcol;
                if (relu) v = fmaxf(v, 0.0f);
                C[(size_t)row * N + col] = f2b(v);
            }
        }
    }
}

// ---------------- fused layer-2 GEMM + heads, atomic combine into d_out ----------------
__global__ __launch_bounds__(256) void gemm2_heads(
    const ushort* __restrict__ hagg_all,  // [g][NN][FH] bf16
    const ushort* __restrict__ W1T,       // [FOUT][FH] bf16
    const float*  __restrict__ b1,        // [FOUT]
    const ushort* __restrict__ WT19,      // [19][FOUT] bf16
    float* __restrict__ out_logits,       // [B,N,18] f32, pre-init with bias
    float* __restrict__ out_values)       // [B,N]    f32, pre-init with bias
{
    __shared__ __align__(16) ushort smem[128 * 136];     // As|Bs chunks; reused as Ct
    __shared__ __align__(16) ushort wt[20][136];         // WT19 slice, row19=0

    char* AsB = (char*)smem;
    char* BsB = (char*)smem + 16384;
    ushort* Ct = smem;                                   // [128][136]

    int bm = blockIdx.x, sp = blockIdx.y, g = blockIdx.z;
    int t = threadIdx.x;
    int lane = t & 63, w = t >> 6;
    int wm = w >> 1, wn = w & 1;
    int l15 = lane & 15, quad = lane >> 4;

    const char* A0 = (const char*)(hagg_all + ((size_t)g * NN + bm * 128) * FH);

    if (t < 136) wt[19][t] = 0;

    int rsub = lane >> 3;
    int colb = (lane & 7) * 16;

    f32x4 hacc[2][2] = {};

    for (int bi = 0; bi < 4; ++bi) {
        int bn = sp * 4 + bi;
        __syncthreads();   // protects Ct/wt of previous iteration from restaging

        for (int idx = t; idx < 19 * 16; idx += 256) {
            int row = idx >> 4, c8 = (idx & 15) * 8;
            *(uint4*)&wt[row][c8] = *(const uint4*)(WT19 + (size_t)row * FOUT + bn * 128 + c8);
        }

        f32x4 acc[4][4] = {};
        const char* Bbase = (const char*)(W1T + (size_t)(bn * 128) * FH);

        for (int k0 = 0; k0 < FH; k0 += 64) {
#pragma unroll
            for (int c = 0; c < 4; ++c) {
                int grp = c * 4 + w;
                int row = grp * 8 + rsub;
                int gcol = k0 * 2 + (colb ^ ((row & 7) << 4));
                gld16(A0 + (size_t)row * (FH * 2) + gcol, AsB + grp * 1024);
                gld16(Bbase + (size_t)row * (FH * 2) + gcol, BsB + grp * 1024);
            }
            __syncthreads();
#pragma unroll
            for (int kk = 0; kk < 64; kk += 32) {
                frag8 af[4], bf[4];
#pragma unroll
                for (int i = 0; i < 4; ++i) {
                    int r = wm * 64 + i * 16 + l15;
                    int cb = (kk * 2 + quad * 16) ^ ((r & 7) << 4);
                    af[i] = *(const frag8*)(AsB + r * 128 + cb);
                }
#pragma unroll
                for (int j = 0; j < 4; ++j) {
                    int r = wn * 64 + j * 16 + l15;
                    int cb = (kk * 2 + quad * 16) ^ ((r & 7) << 4);
                    bf[j] = *(const frag8*)(BsB + r * 128 + cb);
                }
#pragma unroll
                for (int i = 0; i < 4; ++i)
#pragma unroll
                    for (int j = 0; j < 4; ++j)
                        acc[i][j] = __builtin_amdgcn_mfma_f32_16x16x32_bf16(af[i], bf[j], acc[i][j], 0, 0, 0);
            }
            __syncthreads();
        }

#pragma unroll
        for (int j = 0; j < 4; ++j) {
            int colL = wn * 64 + j * 16 + l15;
            float bcol = b1[bn * 128 + colL];
#pragma unroll
            for (int i = 0; i < 4; ++i) {
                int rowL = wm * 64 + i * 16 + quad * 4;
#pragma unroll
                for (int r = 0; r < 4; ++r) {
                    float v = fmaxf(acc[i][j][r] + bcol, 0.0f);
                    Ct[(size_t)(rowL + r) * 136 + colL] = f2b(v);
                }
            }
        }
        __syncthreads();

        int r1 = (l15 < 3) ? (16 + l15) : 19;
#pragma unroll
        for (int kk = 0; kk < 128; kk += 32) {
            frag8 b0 = *(const frag8*)&wt[l15][kk + quad * 8];
            frag8 bO = *(const frag8*)&wt[r1][kk + quad * 8];
#pragma unroll
            for (int mt = 0; mt < 2; ++mt) {
                int row = (w * 2 + mt) * 16 + l15;
                frag8 af = *(const frag8*)&Ct[(size_t)row * 136 + kk + quad * 8];
                hacc[mt][0] = __builtin_amdgcn_mfma_f32_16x16x32_bf16(af, b0, hacc[mt][0], 0, 0, 0);
                hacc[mt][1] = __builtin_amdgcn_mfma_f32_16x16x32_bf16(af, bO, hacc[mt][1], 0, 0, 0);
            }
        }
    }

#pragma unroll
    for (int mt = 0; mt < 2; ++mt) {
#pragma unroll
        for (int r = 0; r < 4; ++r) {
            int node = bm * 128 + (w * 2 + mt) * 16 + quad * 4 + r;
            size_t gn = (size_t)g * NN + node;
            atomicAdd(&out_logits[gn * NLOG + l15], hacc[mt][0][r]);
            if (l15 < 2)       atomicAdd(&out_logits[gn * NLOG + 16 + l15], hacc[mt][1][r]);
            else if (l15 == 2) atomicAdd(&out_values[gn], hacc[mt][1][r]);
        }
    }
}

// ---------------- launcher ----------------
// MEASUREMENT ROUND: gathers launched 4x each (idempotent — deterministic overwrite).
// dur_us - 185.9 = 3*(t_gather1 + t_gather2); any gather >43us surfaces in rocprof top-5.
extern "C" void kernel_launch(void* const* d_in, const int* in_sizes, int n_in,
                              void* d_out, int out_size, void* d_ws, size_t ws_size,
                              hipStream_t stream) {
    const float* nodes = (const float*)d_in[0];
    const int*   edges = (const int*)d_in[1];
    const float* W0 = (const float*)d_in[2];
    const float* b0 = (const float*)d_in[3];
    const float* W1 = (const float*)d_in[4];
    const float* b1 = (const float*)d_in[5];
    const float* Wl = (const float*)d_in[6];
    const float* bl = (const float*)d_in[7];
    const float* Wv = (const float*)d_in[8];
    const float* bv = (const float*)d_in[9];

    float* out_logits = (float*)d_out;
    float* out_values = out_logits + (size_t)BB * NN * NLOG;

    char* ws = (char*)d_ws;
    int*    cursor  = (int*)(ws);                     // 128 KB (becomes cnt)
    ushort* W0T     = (ushort*)(ws + (128 << 10));    // 64 KB
    ushort* W1T     = (ushort*)(ws + (192 << 10));    // 512 KB
    ushort* WT19    = (ushort*)(ws + (704 << 10));    // 38 KB
    uint*   xb      = (uint*)(ws + (1u << 20));       // 8 MB   [B,N,128] bf16
    ushort* bucket  = (ushort*)(ws + (9u << 20));     // 4 MB   [B,N,64] ushort
    ushort* xagg_b  = (ushort*)(ws + (13u << 20));    // 8 MB   [B,N,128] bf16
    ushort* h1b     = (ushort*)(ws + (21u << 20));    // 16 MB  [B,N,256] bf16
    ushort* hagg_b  = (ushort*)(ws + (37u << 20));    // 16 MB  [B,N,256] bf16
    // total ~53 MB

    // 1. prep (x->bf16, weight transposes, cursor zero, out bias-init)
    prep_kernel<<<(PREP_TOTAL + 255) / 256, 256, 0, stream>>>(
        nodes, xb, W0, W0T, W1, W1T, Wl, Wv, WT19, cursor, bl, bv, out_logits, out_values);

    // 2. bucket fill (ushort slots)
    bucket_fill<<<1024, 256, 0, stream>>>(edges, cursor, bucket);

    // 3. layer-1 aggregation — x4 for timing ablation (idempotent)
    for (int rep = 0; rep < 4; ++rep)
        gather_agg_b128<<<(NN / 4) * BB, 256, 0, stream>>>(xb, cursor, bucket, (uint*)xagg_b);

    // 4. layer-1 GEMM
    mfma_gemm<<<dim3(FH / 128, NN / 128, BB), 256, 0, stream>>>(
        xagg_b, W0T, b0, h1b, NN, FH, FOBS, 1);

    // 5. layer-2 aggregation — x4 for timing ablation (idempotent)
    for (int rep = 0; rep < 4; ++rep)
        gather_agg_b256<<<(NN / 4) * BB, 256, 0, stream>>>((const uint2*)h1b, cursor, bucket,
                                                           (uint2*)hagg_b);

    // 6. fused layer-2 GEMM + heads (h2 stays in LDS, heads atomically combined into d_out)
    gemm2_heads<<<dim3(NN / 128, 2, BB), 256, 0, stream>>>(hagg_b, W1T, b1, WT19,
                                                           out_logits, out_values);
}

// Round 8
// 181.282 us; speedup vs baseline: 4.4340x; 1.6872x over previous
//
#include <hip/hip_runtime.h>
#include <hip/hip_bf16.h>

#define BB   4
#define NN   8192
#define EE   65536
#define FOBS 128
#define FH   256
#define FOUT 1024
#define NLOG 18
#define BKT  64

typedef __attribute__((ext_vector_type(8))) short frag8;
typedef __attribute__((ext_vector_type(4))) float f32x4;

__device__ __forceinline__ ushort f2b(float v) {
    __hip_bfloat16 h = __float2bfloat16(v);
    return *reinterpret_cast<ushort*>(&h);
}
__device__ __forceinline__ float blo(uint u) { return __uint_as_float(u << 16); }
__device__ __forceinline__ float bhi(uint u) { return __uint_as_float(u & 0xffff0000u); }

// async global->LDS, 16B per lane; LDS dest is wave-uniform base + lane*16
__device__ __forceinline__ void gld16(const void* g, void* l) {
    __builtin_amdgcn_global_load_lds(
        (const __attribute__((address_space(1))) unsigned*)g,
        (__attribute__((address_space(3))) unsigned*)l, 16, 0, 0);
}

// ---------------- prep: x->bf16 + weight transposes + heads pack + cursor + out init ----------------
#define XB2_N  (BB * NN * FOBS / 2)
#define W0_N   (FOBS * FH)
#define W1_N   (FH * FOUT)
#define WH_N   (19 * FOUT)
#define CUR_N  (BB * NN)
#define OUTI_N (BB * NN * 19)
#define PREP_TOTAL (XB2_N + W0_N + W1_N + WH_N + CUR_N + OUTI_N)

__global__ void prep_kernel(const float* __restrict__ nodes, uint* __restrict__ xb,
                            const float* __restrict__ W0, ushort* __restrict__ W0T,
                            const float* __restrict__ W1, ushort* __restrict__ W1T,
                            const float* __restrict__ Wl, const float* __restrict__ Wv,
                            ushort* __restrict__ WT19, int* __restrict__ cursor,
                            const float* __restrict__ bl, const float* __restrict__ bv,
                            float* __restrict__ out_logits, float* __restrict__ out_values) {
    int idx = blockIdx.x * blockDim.x + threadIdx.x;
    if (idx < XB2_N) {
        float2 xx = ((const float2*)nodes)[idx];
        xb[idx] = (uint)f2b(xx.x) | ((uint)f2b(xx.y) << 16);
        return;
    }
    idx -= XB2_N;
    if (idx < W0_N) {
        int n = idx / FOBS, k = idx - n * FOBS;
        W0T[idx] = f2b(W0[(size_t)k * FH + n]);
        return;
    }
    idx -= W0_N;
    if (idx < W1_N) {
        int n = idx / FH, k = idx - n * FH;
        W1T[idx] = f2b(W1[(size_t)k * FOUT + n]);
        return;
    }
    idx -= W1_N;
    if (idx < WH_N) {
        int o = idx >> 10, k = idx & (FOUT - 1);
        WT19[idx] = f2b((o < NLOG) ? Wl[(size_t)k * NLOG + o] : Wv[k]);
        return;
    }
    idx -= WH_N;
    if (idx < CUR_N) { cursor[idx] = 0; return; }
    idx -= CUR_N;
    if (idx < OUTI_N) {
        int gn = idx / 19, o = idx - gn * 19;
        if (o < NLOG) out_logits[(size_t)gn * NLOG + o] = bl[o];
        else          out_values[gn] = bv[0];
    }
}

// ---------------- bucket fill: direct atomic slot allocation, ushort slots ----------------
__global__ void bucket_fill(const int* __restrict__ edges, int* __restrict__ cursor,
                            ushort* __restrict__ bucket) {
    int blk = blockIdx.x;
    int xcd = blk & 7;
    int g = xcd >> 1;
    int chunk = (blk >> 3) * 2 + (xcd & 1);
    int e = chunk * 256 + threadIdx.x;
    const int* src = edges + (size_t)g * 2 * EE;
    const int* dst = src + EE;
    int d = dst[e];
    int slot = atomicAdd(&cursor[(size_t)g * NN + d], 1);
    if (slot < BKT) bucket[((size_t)g * NN + d) * BKT + slot] = (ushort)src[e];
}

// ---------------- gather 1: quarter-wave rows (16 lanes x 16B = 256B bf16 row) ----------------
// 4 different rows per load instruction; self folded in as virtual row 0 (w = wn^2).
__global__ __launch_bounds__(256) void gather_agg_b128(
    const uint4* __restrict__ xb4_all, const int* __restrict__ cnt_all,
    const ushort* __restrict__ bucket, uint4* __restrict__ agg_all)
{
    int blk = blockIdx.x;
    int xcd = blk & 7;
    int g = xcd >> 1;
    int chunk = (blk >> 3) * 2 + (xcd & 1);
    int wv = threadIdx.x >> 6, lane = threadIdx.x & 63;
    int n = chunk * 4 + wv;
    int q = lane >> 4, sub = lane & 15;
    const uint4* xb4 = xb4_all + (size_t)g * NN * 16;
    const int* cnt = cnt_all + (size_t)g * NN;
    const ushort* bkt = bucket + ((size_t)g * NN + n) * BKT;

    int cn = cnt[n];
    float wn = rsqrtf((float)cn + 1.0f);
    int total = min(cn, BKT) + 1;        // virtual rows: 0 = self, 1..deg = bucket

    float acc[8] = {};
    for (int base = 0; base < total; base += 8) {
#pragma unroll
        for (int j = 0; j < 2; ++j) {
            int vr = base + q + 4 * j;
            bool ok = vr < total;
            int src = (!ok || vr == 0) ? n : (int)bkt[vr - 1];
            float w = ok ? rsqrtf((float)cnt[src] + 1.0f) * wn : 0.0f;
            uint4 r = xb4[(size_t)src * 16 + sub];
            acc[0] += w * blo(r.x); acc[1] += w * bhi(r.x);
            acc[2] += w * blo(r.y); acc[3] += w * bhi(r.y);
            acc[4] += w * blo(r.z); acc[5] += w * bhi(r.z);
            acc[6] += w * blo(r.w); acc[7] += w * bhi(r.w);
        }
    }
#pragma unroll
    for (int e = 0; e < 8; ++e) {
        acc[e] += __shfl_xor(acc[e], 16);
        acc[e] += __shfl_xor(acc[e], 32);
    }
    if (lane < 16) {
        uint4 o;
        o.x = (uint)f2b(acc[0]) | ((uint)f2b(acc[1]) << 16);
        o.y = (uint)f2b(acc[2]) | ((uint)f2b(acc[3]) << 16);
        o.z = (uint)f2b(acc[4]) | ((uint)f2b(acc[5]) << 16);
        o.w = (uint)f2b(acc[6]) | ((uint)f2b(acc[7]) << 16);
        agg_all[((size_t)g * NN + n) * 16 + sub] = o;
    }
}

// ---------------- gather 2: half-wave rows (32 lanes x 16B = 512B bf16 row) ----------------
__global__ __launch_bounds__(256) void gather_agg_b256(
    const uint4* __restrict__ xb4_all, const int* __restrict__ cnt_all,
    const ushort* __restrict__ bucket, uint4* __restrict__ agg_all)
{
    int blk = blockIdx.x;
    int xcd = blk & 7;
    int g = xcd >> 1;
    int chunk = (blk >> 3) * 2 + (xcd & 1);
    int wv = threadIdx.x >> 6, lane = threadIdx.x & 63;
    int n = chunk * 4 + wv;
    int h = lane >> 5, sub = lane & 31;
    const uint4* xb4 = xb4_all + (size_t)g * NN * 32;
    const int* cnt = cnt_all + (size_t)g * NN;
    const ushort* bkt = bucket + ((size_t)g * NN + n) * BKT;

    int cn = cnt[n];
    float wn = rsqrtf((float)cn + 1.0f);
    int total = min(cn, BKT) + 1;

    float acc[8] = {};
    for (int base = 0; base < total; base += 8) {
#pragma unroll
        for (int j = 0; j < 4; ++j) {
            int vr = base + h + 2 * j;
            bool ok = vr < total;
            int src = (!ok || vr == 0) ? n : (int)bkt[vr - 1];
            float w = ok ? rsqrtf((float)cnt[src] + 1.0f) * wn : 0.0f;
            uint4 r = xb4[(size_t)src * 32 + sub];
            acc[0] += w * blo(r.x); acc[1] += w * bhi(r.x);
            acc[2] += w * blo(r.y); acc[3] += w * bhi(r.y);
            acc[4] += w * blo(r.z); acc[5] += w * bhi(r.z);
            acc[6] += w * blo(r.w); acc[7] += w * bhi(r.w);
        }
    }
#pragma unroll
    for (int e = 0; e < 8; ++e)
        acc[e] += __shfl_xor(acc[e], 32);
    if (lane < 32) {
        uint4 o;
        o.x = (uint)f2b(acc[0]) | ((uint)f2b(acc[1]) << 16);
        o.y = (uint)f2b(acc[2]) | ((uint)f2b(acc[3]) << 16);
        o.z = (uint)f2b(acc[4]) | ((uint)f2b(acc[5]) << 16);
        o.w = (uint)f2b(acc[6]) | ((uint)f2b(acc[7]) << 16);
        agg_all[((size_t)g * NN + n) * 32 + sub] = o;
    }
}

// ---------------- MFMA GEMM (layer 1, batched via blockIdx.z) ----------------
__global__ __launch_bounds__(256) void mfma_gemm(
    const ushort* __restrict__ A_all, const ushort* __restrict__ BT,
    const float* __restrict__ bias, ushort* __restrict__ C_all,
    int M, int N, int K, int relu)
{
    __shared__ __align__(16) ushort As[128 * 64];
    __shared__ __align__(16) ushort Bs[128 * 64];

    int g = blockIdx.z;
    const ushort* A = A_all + (size_t)g * M * K;
    ushort* C = C_all + (size_t)g * M * N;

    int t = threadIdx.x;
    int bn = blockIdx.x, bm = blockIdx.y;
    int lane = t & 63, w = t >> 6;
    int wm = w >> 1, wn = w & 1;
    int l15 = lane & 15, quad = lane >> 4;

    f32x4 acc[4][4] = {};

    const char* Abase = (const char*)(A + (size_t)(bm * 128) * K);
    const char* Bbase = (const char*)(BT + (size_t)(bn * 128) * K);
    size_t rstride = (size_t)K * 2;

    int rsub = lane >> 3;
    int colb = (lane & 7) * 16;

    for (int k0 = 0; k0 < K; k0 += 64) {
#pragma unroll
        for (int c = 0; c < 4; ++c) {
            int grp = c * 4 + w;
            int row = grp * 8 + rsub;
            int gcol = k0 * 2 + (colb ^ ((row & 7) << 4));
            gld16(Abase + (size_t)row * rstride + gcol, (char*)As + grp * 1024);
            gld16(Bbase + (size_t)row * rstride + gcol, (char*)Bs + grp * 1024);
        }
        __syncthreads();
#pragma unroll
        for (int kk = 0; kk < 64; kk += 32) {
            frag8 af[4], bf[4];
#pragma unroll
            for (int i = 0; i < 4; ++i) {
                int r = wm * 64 + i * 16 + l15;
                int cb = (kk * 2 + quad * 16) ^ ((r & 7) << 4);
                af[i] = *(const frag8*)((const char*)As + r * 128 + cb);
            }
#pragma unroll
            for (int j = 0; j < 4; ++j) {
                int r = wn * 64 + j * 16 + l15;
                int cb = (kk * 2 + quad * 16) ^ ((r & 7) << 4);
                bf[j] = *(const frag8*)((const char*)Bs + r * 128 + cb);
            }
#pragma unroll
            for (int i = 0; i < 4; ++i)
#pragma unroll
                for (int j = 0; j < 4; ++j)
                    acc[i][j] = __builtin_amdgcn_mfma_f32_16x16x32_bf16(af[i], bf[j], acc[i][j], 0, 0, 0);
        }
        __syncthreads();
    }

#pragma unroll
    for (int i = 0; i < 4; ++i) {
#pragma unroll
        for (int j = 0; j < 4; ++j) {
            int col = bn * 128 + wn * 64 + j * 16 + l15;
            float bcol = bias[col];
#pragma unroll
            for (int r = 0; r < 4; ++r) {
                int row = bm * 128 + wm * 64 + i * 16 + quad * 4 + r;
                float v = acc[i][j][r] + bcol;
                if (relu) v = fmaxf(v, 0.0f);
                C[(size_t)row * N + col] = f2b(v);
            }
        }
    }
}

// ---------------- fused layer-2 GEMM + heads, atomic combine into d_out ----------------
__global__ __launch_bounds__(256) void gemm2_heads(
    const ushort* __restrict__ hagg_all,  // [g][NN][FH] bf16
    const ushort* __restrict__ W1T,       // [FOUT][FH] bf16
    const float*  __restrict__ b1,        // [FOUT]
    const ushort* __restrict__ WT19,      // [19][FOUT] bf16
    float* __restrict__ out_logits,       // [B,N,18] f32, pre-init with bias
    float* __restrict__ out_values)       // [B,N]    f32, pre-init with bias
{
    __shared__ __align__(16) ushort smem[128 * 136];     // As|Bs chunks; reused as Ct
    __shared__ __align__(16) ushort wt[20][136];         // WT19 slice, row19=0

    char* AsB = (char*)smem;
    char* BsB = (char*)smem + 16384;
    ushort* Ct = smem;                                   // [128][136]

    int bm = blockIdx.x, sp = blockIdx.y, g = blockIdx.z;
    int t = threadIdx.x;
    int lane = t & 63, w = t >> 6;
    int wm = w >> 1, wn = w & 1;
    int l15 = lane & 15, quad = lane >> 4;

    const char* A0 = (const char*)(hagg_all + ((size_t)g * NN + bm * 128) * FH);

    if (t < 136) wt[19][t] = 0;

    int rsub = lane >> 3;
    int colb = (lane & 7) * 16;

    f32x4 hacc[2][2] = {};

    for (int bi = 0; bi < 4; ++bi) {
        int bn = sp * 4 + bi;
        __syncthreads();   // protects Ct/wt of previous iteration from restaging

        for (int idx = t; idx < 19 * 16; idx += 256) {
            int row = idx >> 4, c8 = (idx & 15) * 8;
            *(uint4*)&wt[row][c8] = *(const uint4*)(WT19 + (size_t)row * FOUT + bn * 128 + c8);
        }

        f32x4 acc[4][4] = {};
        const char* Bbase = (const char*)(W1T + (size_t)(bn * 128) * FH);

        for (int k0 = 0; k0 < FH; k0 += 64) {
#pragma unroll
            for (int c = 0; c < 4; ++c) {
                int grp = c * 4 + w;
                int row = grp * 8 + rsub;
                int gcol = k0 * 2 + (colb ^ ((row & 7) << 4));
                gld16(A0 + (size_t)row * (FH * 2) + gcol, AsB + grp * 1024);
                gld16(Bbase + (size_t)row * (FH * 2) + gcol, BsB + grp * 1024);
            }
            __syncthreads();
#pragma unroll
            for (int kk = 0; kk < 64; kk += 32) {
                frag8 af[4], bf[4];
#pragma unroll
                for (int i = 0; i < 4; ++i) {
                    int r = wm * 64 + i * 16 + l15;
                    int cb = (kk * 2 + quad * 16) ^ ((r & 7) << 4);
                    af[i] = *(const frag8*)(AsB + r * 128 + cb);
                }
#pragma unroll
                for (int j = 0; j < 4; ++j) {
                    int r = wn * 64 + j * 16 + l15;
                    int cb = (kk * 2 + quad * 16) ^ ((r & 7) << 4);
                    bf[j] = *(const frag8*)(BsB + r * 128 + cb);
                }
#pragma unroll
                for (int i = 0; i < 4; ++i)
#pragma unroll
                    for (int j = 0; j < 4; ++j)
                        acc[i][j] = __builtin_amdgcn_mfma_f32_16x16x32_bf16(af[i], bf[j], acc[i][j], 0, 0, 0);
            }
            __syncthreads();
        }

#pragma unroll
        for (int j = 0; j < 4; ++j) {
            int colL = wn * 64 + j * 16 + l15;
            float bcol = b1[bn * 128 + colL];
#pragma unroll
            for (int i = 0; i < 4; ++i) {
                int rowL = wm * 64 + i * 16 + quad * 4;
#pragma unroll
                for (int r = 0; r < 4; ++r) {
                    float v = fmaxf(acc[i][j][r] + bcol, 0.0f);
                    Ct[(size_t)(rowL + r) * 136 + colL] = f2b(v);
                }
            }
        }
        __syncthreads();

        int r1 = (l15 < 3) ? (16 + l15) : 19;
#pragma unroll
        for (int kk = 0; kk < 128; kk += 32) {
            frag8 b0 = *(const frag8*)&wt[l15][kk + quad * 8];
            frag8 bO = *(const frag8*)&wt[r1][kk + quad * 8];
#pragma unroll
            for (int mt = 0; mt < 2; ++mt) {
                int row = (w * 2 + mt) * 16 + l15;
                frag8 af = *(const frag8*)&Ct[(size_t)row * 136 + kk + quad * 8];
                hacc[mt][0] = __builtin_amdgcn_mfma_f32_16x16x32_bf16(af, b0, hacc[mt][0], 0, 0, 0);
                hacc[mt][1] = __builtin_amdgcn_mfma_f32_16x16x32_bf16(af, bO, hacc[mt][1], 0, 0, 0);
            }
        }
    }

#pragma unroll
    for (int mt = 0; mt < 2; ++mt) {
#pragma unroll
        for (int r = 0; r < 4; ++r) {
            int node = bm * 128 + (w * 2 + mt) * 16 + quad * 4 + r;
            size_t gn = (size_t)g * NN + node;
            atomicAdd(&out_logits[gn * NLOG + l15], hacc[mt][0][r]);
            if (l15 < 2)       atomicAdd(&out_logits[gn * NLOG + 16 + l15], hacc[mt][1][r]);
            else if (l15 == 2) atomicAdd(&out_values[gn], hacc[mt][1][r]);
        }
    }
}

// ---------------- launcher ----------------
extern "C" void kernel_launch(void* const* d_in, const int* in_sizes, int n_in,
                              void* d_out, int out_size, void* d_ws, size_t ws_size,
                              hipStream_t stream) {
    const float* nodes = (const float*)d_in[0];
    const int*   edges = (const int*)d_in[1];
    const float* W0 = (const float*)d_in[2];
    const float* b0 = (const float*)d_in[3];
    const float* W1 = (const float*)d_in[4];
    const float* b1 = (const float*)d_in[5];
    const float* Wl = (const float*)d_in[6];
    const float* bl = (const float*)d_in[7];
    const float* Wv = (const float*)d_in[8];
    const float* bv = (const float*)d_in[9];

    float* out_logits = (float*)d_out;
    float* out_values = out_logits + (size_t)BB * NN * NLOG;

    char* ws = (char*)d_ws;
    int*    cursor  = (int*)(ws);                     // 128 KB (becomes cnt)
    ushort* W0T     = (ushort*)(ws + (128 << 10));    // 64 KB
    ushort* W1T     = (ushort*)(ws + (192 << 10));    // 512 KB
    ushort* WT19    = (ushort*)(ws + (704 << 10));    // 38 KB
    uint*   xb      = (uint*)(ws + (1u << 20));       // 8 MB   [B,N,128] bf16
    ushort* bucket  = (ushort*)(ws + (9u << 20));     // 4 MB   [B,N,64] ushort
    ushort* xagg_b  = (ushort*)(ws + (13u << 20));    // 8 MB   [B,N,128] bf16
    ushort* h1b     = (ushort*)(ws + (21u << 20));    // 16 MB  [B,N,256] bf16
    ushort* hagg_b  = (ushort*)(ws + (37u << 20));    // 16 MB  [B,N,256] bf16
    // total ~53 MB

    // 1. prep (x->bf16, weight transposes, cursor zero, out bias-init)
    prep_kernel<<<(PREP_TOTAL + 255) / 256, 256, 0, stream>>>(
        nodes, xb, W0, W0T, W1, W1T, Wl, Wv, WT19, cursor, bl, bv, out_logits, out_values);

    // 2. bucket fill (ushort slots)
    bucket_fill<<<1024, 256, 0, stream>>>(edges, cursor, bucket);

    // 3. layer-1 aggregation (quarter-wave 16B rows)
    gather_agg_b128<<<(NN / 4) * BB, 256, 0, stream>>>((const uint4*)xb, cursor, bucket,
                                                       (uint4*)xagg_b);

    // 4. layer-1 GEMM
    mfma_gemm<<<dim3(FH / 128, NN / 128, BB), 256, 0, stream>>>(
        xagg_b, W0T, b0, h1b, NN, FH, FOBS, 1);

    // 5. layer-2 aggregation (half-wave 16B rows)
    gather_agg_b256<<<(NN / 4) * BB, 256, 0, stream>>>((const uint4*)h1b, cursor, bucket,
                                                       (uint4*)hagg_b);

    // 6. fused layer-2 GEMM + heads (h2 stays in LDS, heads atomically combined into d_out)
    gemm2_heads<<<dim3(NN / 128, 2, BB), 256, 0, stream>>>(hagg_b, W1T, b1, WT19,
                                                           out_logits, out_values);
}